// Round 5
// baseline (215.963 us; speedup 1.0000x reference)
//
#include <hip/hip_runtime.h>

// ExpFlow: scaling-and-squaring exponentiation of a velocity field.
// x: [N=2, C=3, 128^3] f32. u0 = x/32; 5x: u <- u + warp(u, id+u).
//
// R12: d-paired block tiling + s5 split (gather->fp16, then stream-expand).
// Model (R7-R11): mixed gather kernels are bound by TCC TRANSACTION rate,
// not bytes (fill kernels stream 6.5 TB/s; we sit at ~1.4). Largest
// redundant transaction source: z-axis -- each row region is fetched as
// (z0) by plane-d blocks and as (z0+1) by plane-(d-1) blocks on different
// CUs at different times. Fix: block tile = 128w x 2h x 2d, so the two
// z-fetches coincide on one CU (L1 hit, no second TCC transaction).
// s5 split: the 50 MB f32 SoA write moves out of the transaction-bound
// gather kernel into a pure streaming expand (~13 us at stream rate).
// Layout/packing (6 B/voxel pairs), LIFO alternation, lerp order: R11.

namespace {
constexpr int kD = 128, kH = 128, kW = 128, kN = 2, kC = 3;
constexpr int kPlane = kD * kH * kW;          // 2^21 voxels per batch
constexpr int kVol   = kC * kPlane;
constexpr int kTotalVox   = kN * kPlane;      // 4,194,304
constexpr int kTotalElems = kN * kVol;        // 12,582,912 f32 (SoA buffer)
constexpr size_t kBatchBytes = (size_t)kPlane * 6;   // 12,582,912 B (pairs)
constexpr float kScale0 = 1.0f / 32.0f;
}

typedef float f32x2 __attribute__((ext_vector_type(2)));
typedef unsigned int u32;
typedef u32 u32x3 __attribute__((ext_vector_type(3), aligned(4)));
typedef u32 u32x4a4 __attribute__((ext_vector_type(4), aligned(4)));

static __device__ __forceinline__ float h2f(u32 bits) {
    _Float16 v;
    unsigned short s = (unsigned short)bits;
    __builtin_memcpy(&v, &s, 2);
    return (float)v;               // v_cvt_f32_f16
}
static __device__ __forceinline__ u32 f2h2(float a, float b) {
    _Float16 ha = (_Float16)a, hb = (_Float16)b;   // v_cvt_f16_f32 (RTN)
    unsigned short sa, sb;
    __builtin_memcpy(&sa, &ha, 2);
    __builtin_memcpy(&sb, &hb, 2);
    return (u32)sa | ((u32)sb << 16);
}

// XCD-slab swizzle with d-paired block tiling.
// 8192 blocks; b&7 = XCD (HW round-robin); 16 slabs (2 batches x 8 d-slabs
// of 16 planes); XCD j owns slabs j, j+8. Within a slab, a block covers a
// 128w x 2h x 2d tile: tid = [dd:1][hh:1][wl:6], seq9 = [dp:3][hp:6].
// The dd=0/dd=1 halves share their z-neighbor rows -> L1 dedup.
// REV flips the per-XCD sweep (LIFO between consecutive steps).
static __device__ __forceinline__ int slab_rr(int* n_out, bool rev) {
    int b    = blockIdx.x;
    int xcd  = b & 7;
    int seq  = b >> 3;                    // 0..1023
    if (rev) seq = 1023 - seq;
    int slab = xcd | ((seq >> 9) << 3);   // 0..15
    *n_out   = slab >> 3;                 // batch
    int dblk = slab & 7;                  // d-slab within batch
    int s9   = seq & 511;
    int hp   = s9 & 63;                   // h-pair index
    int dp   = (s9 >> 6) & 7;             // d-pair within slab
    int wl   = threadIdx.x & 63;
    int hh   = (threadIdx.x >> 6) & 1;
    int dd   = threadIdx.x >> 7;
    int d    = (dblk << 4) | (dp << 1) | dd;
    int h    = (hp << 1) | hh;
    return (d << 14) | (h << 7) | (wl << 1);   // within-batch even voxel
}

// ---------------------------------------------------------------------------
// Transcode: f32 SoA x (scale fused) -> pair-packed fp16 (12B/pair).
// ---------------------------------------------------------------------------
__global__ __launch_bounds__(256) void transcode_kernel(const float* __restrict__ x,
                                                        void* __restrict__ aos) {
    int n;
    int rr = slab_rr(&n, false);
    const float* __restrict__ ub = x + (size_t)n * kVol;
    f32x2 bx = *(const f32x2*)(ub + rr);
    f32x2 by = *(const f32x2*)(ub + kPlane + rr);
    f32x2 bz = *(const f32x2*)(ub + 2 * kPlane + rr);
    bx *= kScale0; by *= kScale0; bz *= kScale0;
    u32x3 s;
    s.x = f2h2(bx.x, by.x);      // x0,y0
    s.y = f2h2(bz.x, bz.y);      // z0,z1
    s.z = f2h2(bx.y, by.y);      // x1,y1
    char* ob = (char*)aos + (size_t)n * kBatchBytes;
    *(u32x3*)(ob + (size_t)(rr >> 1) * 12) = s;    // 12B store, 4B-aligned
}

// ---------------------------------------------------------------------------
// Expand: pair-packed fp16 -> f32 SoA d_out. Pure streaming (no gathers):
// 25 MB read + 50 MB write at stream rate.
// ---------------------------------------------------------------------------
__global__ __launch_bounds__(256) void expand_kernel(const void* __restrict__ uin,
                                                     float* __restrict__ out) {
    int n;
    int rr = slab_rr(&n, false);
    const char* __restrict__ ubase = (const char*)uin + (size_t)n * kBatchBytes;
    u32x3 q = *(const u32x3*)(ubase + (size_t)(rr >> 1) * 12);
    float* __restrict__ obp = out + (size_t)n * kVol;
    *(f32x2*)(obp + rr)              = f32x2{h2f(q.x & 0xffffu), h2f(q.z & 0xffffu)};
    *(f32x2*)(obp + kPlane + rr)     = f32x2{h2f(q.x >> 16),     h2f(q.z >> 16)};
    *(f32x2*)(obp + 2 * kPlane + rr) = f32x2{h2f(q.y & 0xffffu), h2f(q.y >> 16)};
}

// ---------------------------------------------------------------------------
// Warp step on pair-packed fp16 -> pair-packed fp16.
// ---------------------------------------------------------------------------
template <bool REV>
__global__ __launch_bounds__(256) void step_p6h(const void* __restrict__ uin,
                                                void* __restrict__ uout) {
    int n;
    int rr = slab_rr(&n, REV);
    int w = rr & 127;
    int h = (rr >> 7) & 127;
    int d = rr >> 14;

    const char* __restrict__ ubase = (const char*)uin + (size_t)n * kBatchBytes;

    // Base velocity for voxels (rr, rr+1): one 12B dwordx3 (even pair:
    // d0=x0y0, d1=z0z1, d2=x1y1).
    u32x3 bq = *(const u32x3*)(ubase + (size_t)(rr >> 1) * 12);
    float vx[2], vy[2], vz[2];
    vx[0] = h2f(bq.x & 0xffffu); vy[0] = h2f(bq.x >> 16); vz[0] = h2f(bq.y & 0xffffu);
    vx[1] = h2f(bq.z & 0xffffu); vy[1] = h2f(bq.z >> 16); vz[1] = h2f(bq.y >> 16);

    // Cube offsets + weights (border clamp folded into low corner).
    int   o[2];
    float wxa[2], wya[2], wza[2];
    #pragma unroll
    for (int j = 0; j < 2; ++j) {
        float px = fminf(fmaxf((float)(w + j) + vx[j] * 63.5f, 0.0f), 127.0f);
        float py = fminf(fmaxf((float)h       + vy[j] * 63.5f, 0.0f), 127.0f);
        float pz = fminf(fmaxf((float)d       + vz[j] * 63.5f, 0.0f), 127.0f);
        int x0 = min((int)floorf(px), 126);
        int y0 = min((int)floorf(py), 126);
        int z0 = min((int)floorf(pz), 126);
        wxa[j] = px - (float)x0;
        wya[j] = py - (float)y0;
        wza[j] = pz - (float)z0;
        o[j] = (z0 << 14) + (y0 << 7) + x0;
    }

    // Row byte offsets: +128 voxels = 64 pairs = 768B; +16384 voxels = 98304B.
    const int rowbyte[4] = {0, 768, 98304, 99072};
    float res[3][2];
    #pragma unroll
    for (int j = 0; j < 2; ++j) {
        float wx = wxa[j], wy = wya[j], wz = wza[j];
        float omx = 1.0f - wx, omy = 1.0f - wy, omz = 1.0f - wz;
        u32 pb = (u32)(o[j] & 1);
        size_t gb = (size_t)(o[j] >> 1) * 12 + (pb << 2);
        float cr[4][3];
        #pragma unroll
        for (int r = 0; r < 4; ++r) {
            u32x4a4 q = *(const u32x4a4*)(ubase + gb + rowbyte[r]);
            // even (pb=0): q = d0(k) d1(k) d2(k) d0(k+1)
            // odd  (pb=1): q = d1(k) d2(k) d0(k+1) d1(k+1)
            u32 xy0 = pb ? q.y : q.x;
            u32 z0b = pb ? (q.x >> 16) : (q.y & 0xffffu);
            u32 xy1 = q.z;
            u32 z1b = pb ? (q.w & 0xffffu) : (q.y >> 16);
            float ax = h2f(xy0 & 0xffffu), ay = h2f(xy0 >> 16), az = h2f(z0b);
            float bx = h2f(xy1 & 0xffffu), by = h2f(xy1 >> 16), bz = h2f(z1b);
            cr[r][0] = ax * omx + bx * wx;
            cr[r][1] = ay * omx + by * wx;
            cr[r][2] = az * omx + bz * wx;
        }
        #pragma unroll
        for (int c = 0; c < 3; ++c) {
            float c0 = cr[0][c] * omy + cr[1][c] * wy;
            float c1 = cr[2][c] * omy + cr[3][c] * wy;
            float base = (c == 0) ? vx[j] : (c == 1) ? vy[j] : vz[j];
            res[c][j] = base + (c0 * omz + c1 * wz);
        }
    }

    u32x3 s;
    s.x = f2h2(res[0][0], res[1][0]);   // x0,y0
    s.y = f2h2(res[2][0], res[2][1]);   // z0,z1
    s.z = f2h2(res[0][1], res[1][1]);   // x1,y1
    char* ob = (char*)uout + (size_t)n * kBatchBytes;
    *(u32x3*)(ob + (size_t)(rr >> 1) * 12) = s;
}

// ---------------------------------------------------------------------------
// R7 f32 SoA kernel retained verbatim as the small-workspace fallback.
// ---------------------------------------------------------------------------
template <bool SCALED>
__global__ __launch_bounds__(256) void step_kernel(const float* __restrict__ u,
                                                   float* __restrict__ out) {
    int b    = blockIdx.x;
    int xcd  = b & 7;
    int seq  = b >> 3;
    int slab = xcd | ((seq >> 9) << 3);
    int n    = slab >> 3;
    int dblk = slab & 7;
    int vo   = ((seq & 511) << 9) | (threadIdx.x << 1);
    int rr   = (dblk << 18) | vo;

    int w = rr & 127;
    int h = (rr >> 7) & 127;
    int d = rr >> 14;

    const float* __restrict__ ub = u + (size_t)n * kVol;

    f32x2 bx = *(const f32x2*)(ub + rr);
    f32x2 by = *(const f32x2*)(ub + kPlane + rr);
    f32x2 bz = *(const f32x2*)(ub + 2 * kPlane + rr);
    if (SCALED) { bx *= kScale0; by *= kScale0; bz *= kScale0; }

    int   o[2];
    float wxa[2], wya[2], wza[2];
    #pragma unroll
    for (int j = 0; j < 2; ++j) {
        float vx = (j == 0) ? bx.x : bx.y;
        float vy = (j == 0) ? by.x : by.y;
        float vz = (j == 0) ? bz.x : bz.y;
        float px = fminf(fmaxf((float)(w + j) + vx * 63.5f, 0.0f), 127.0f);
        float py = fminf(fmaxf((float)h       + vy * 63.5f, 0.0f), 127.0f);
        float pz = fminf(fmaxf((float)d       + vz * 63.5f, 0.0f), 127.0f);
        int x0 = min((int)floorf(px), 126);
        int y0 = min((int)floorf(py), 126);
        int z0 = min((int)floorf(pz), 126);
        wxa[j] = px - (float)x0;
        wya[j] = py - (float)y0;
        wza[j] = pz - (float)z0;
        o[j] = (z0 << 14) + (y0 << 7) + x0;
    }

    const int rowoff[4] = {0, 128, 16384, 16512};
    float res[3][2];
    #pragma unroll
    for (int j = 0; j < 2; ++j) {
        float wx = wxa[j], wy = wya[j], wz = wza[j];
        float omx = 1.0f - wx, omy = 1.0f - wy, omz = 1.0f - wz;
        #pragma unroll
        for (int c = 0; c < 3; ++c) {
            const float* __restrict__ up = ub + c * kPlane;
            f32x2 v00 = *(const f32x2*)(up + o[j] + rowoff[0]);
            f32x2 v01 = *(const f32x2*)(up + o[j] + rowoff[1]);
            f32x2 v10 = *(const f32x2*)(up + o[j] + rowoff[2]);
            f32x2 v11 = *(const f32x2*)(up + o[j] + rowoff[3]);
            if (SCALED) { v00 *= kScale0; v01 *= kScale0; v10 *= kScale0; v11 *= kScale0; }
            float c00 = v00.x * omx + v00.y * wx;
            float c01 = v01.x * omx + v01.y * wx;
            float c10 = v10.x * omx + v10.y * wx;
            float c11 = v11.x * omx + v11.y * wx;
            float c0 = c00 * omy + c01 * wy;
            float c1 = c10 * omy + c11 * wy;
            float s  = c0 * omz + c1 * wz;
            float base = (c == 0) ? ((j == 0) ? bx.x : bx.y)
                       : (c == 1) ? ((j == 0) ? by.x : by.y)
                                  : ((j == 0) ? bz.x : bz.y);
            res[c][j] = base + s;
        }
    }

    float* __restrict__ ob = out + (size_t)n * kVol;
    *(f32x2*)(ob + rr)              = f32x2{res[0][0], res[0][1]};
    *(f32x2*)(ob + kPlane + rr)     = f32x2{res[1][0], res[1][1]};
    *(f32x2*)(ob + 2 * kPlane + rr) = f32x2{res[2][0], res[2][1]};
}

extern "C" void kernel_launch(void* const* d_in, const int* in_sizes, int n_in,
                              void* d_out, int out_size, void* d_ws, size_t ws_size,
                              hipStream_t stream) {
    const float* x = (const float*)d_in[0];
    float* out = (float*)d_out;

    const int grd = kTotalVox / (256 * 2);   // 8192 blocks
    // Two pair-packed buffers: 2 x 25,165,824 B (+4KB slack).
    const size_t need_p6 = (size_t)2 * kN * kBatchBytes + 4096;

    if (ws_size >= need_p6) {
        char* A = (char*)d_ws;
        char* B = A + (size_t)kN * kBatchBytes;
        transcode_kernel<<<grd, 256, 0, stream>>>(x, A);        // u0 (asc)
        step_p6h<true ><<<grd, 256, 0, stream>>>(A, B);         // s1 (desc)
        step_p6h<false><<<grd, 256, 0, stream>>>(B, A);         // s2 (asc)
        step_p6h<true ><<<grd, 256, 0, stream>>>(A, B);         // s3 (desc)
        step_p6h<false><<<grd, 256, 0, stream>>>(B, A);         // s4 (asc)
        step_p6h<true ><<<grd, 256, 0, stream>>>(A, B);         // s5 (desc)
        expand_kernel<<<grd, 256, 0, stream>>>(B, out);         // stream expand
    } else {
        // R3-parity f32 fallback: x->out->ws->out->ws->out.
        float* ws = (float*)d_ws;
        step_kernel<true ><<<grd, 256, 0, stream>>>(x,   out);
        step_kernel<false><<<grd, 256, 0, stream>>>(out, ws);
        step_kernel<false><<<grd, 256, 0, stream>>>(ws,  out);
        step_kernel<false><<<grd, 256, 0, stream>>>(out, ws);
        step_kernel<false><<<grd, 256, 0, stream>>>(ws,  out);
    }
}

// Round 6
// 202.339 us; speedup vs baseline: 1.0673x; 1.0673x over previous
//
#include <hip/hip_runtime.h>

// ExpFlow: scaling-and-squaring exponentiation of a velocity field.
// x: [N=2, C=3, 128^3] f32. u0 = x/32; 5x: u <- u + warp(u, id+u).
//
// R13: revert s5-split (R12 regression) + 4h x 4d block tiles (1024 thr).
// Surviving model: gather kernels are bound by L2-transaction traffic;
// the dominant redundancy is neighbor-ROW refetch across blocks. Gather
// displacements are tiny (std 0.2..3.2 voxels for s1..s5), so a block
// tile of (128w x Th x Td) touches ~(Th+1)(Td+1) rows for Th*Td owned:
// R11 4x1 -> 2.5x, R12 2x2 -> 2.25x (undetectable delta, consistent),
// R13 4x4 -> 1.56x (38% cut of gather lines -- a measurable dose).
// Also: nontemporal load of x / store of d_out to protect L2 residency
// of the live packed buffers. Packing (6 B/voxel pairs), LIFO sweep,
// lerp order, numerics: identical to R11 (absmax 1.95e-3).

namespace {
constexpr int kD = 128, kH = 128, kW = 128, kN = 2, kC = 3;
constexpr int kPlane = kD * kH * kW;          // 2^21 voxels per batch
constexpr int kVol   = kC * kPlane;
constexpr int kTotalVox   = kN * kPlane;      // 4,194,304
constexpr int kTotalElems = kN * kVol;        // 12,582,912 f32 (SoA buffer)
constexpr size_t kBatchBytes = (size_t)kPlane * 6;   // 12,582,912 B (pairs)
constexpr float kScale0 = 1.0f / 32.0f;
}

typedef float f32x2 __attribute__((ext_vector_type(2)));
typedef unsigned int u32;
typedef u32 u32x3 __attribute__((ext_vector_type(3), aligned(4)));
typedef u32 u32x4a4 __attribute__((ext_vector_type(4), aligned(4)));

static __device__ __forceinline__ float h2f(u32 bits) {
    _Float16 v;
    unsigned short s = (unsigned short)bits;
    __builtin_memcpy(&v, &s, 2);
    return (float)v;               // v_cvt_f32_f16
}
static __device__ __forceinline__ u32 f2h2(float a, float b) {
    _Float16 ha = (_Float16)a, hb = (_Float16)b;   // v_cvt_f16_f32 (RTN)
    unsigned short sa, sb;
    __builtin_memcpy(&sa, &ha, 2);
    __builtin_memcpy(&sb, &hb, 2);
    return (u32)sa | ((u32)sb << 16);
}

// XCD-slab swizzle, 1024-thread blocks, tile = 128w x 4h x 4d.
// 2048 blocks; b&7 = XCD (HW round-robin); 16 slabs (2 batches x 8
// d-slabs of 16 planes); XCD j owns slabs j, j+8. Within a slab:
// 4 d-tiles x 32 h-tiles; within a block: tid = [dd:2][hh:2][wl:6].
// REV flips the per-XCD sweep (LIFO between consecutive steps).
static __device__ __forceinline__ int slab_rr(int* n_out, bool rev) {
    int b    = blockIdx.x;                 // 0..2047
    int xcd  = b & 7;
    int seq  = b >> 3;                     // 0..255
    if (rev) seq = 255 - seq;
    int slab = xcd | (((seq >> 7) & 1) << 3);   // 0..15
    *n_out   = slab >> 3;                  // batch
    int dblk = slab & 7;                   // d-slab within batch
    int s7   = seq & 127;
    int ht   = s7 & 31;                    // h-tile
    int dt   = (s7 >> 5) & 3;              // d-tile within slab
    int wl   = threadIdx.x & 63;
    int hh   = (threadIdx.x >> 6) & 3;
    int dd   = (threadIdx.x >> 8) & 3;
    int d    = (dblk << 4) | (dt << 2) | dd;
    int h    = (ht << 2) | hh;
    return (d << 14) | (h << 7) | (wl << 1);   // within-batch even voxel
}

// ---------------------------------------------------------------------------
// Transcode: f32 SoA x (scale fused) -> pair-packed fp16 (12B/pair).
// nt loads: x is read exactly once; don't evict packed buffers from L2.
// ---------------------------------------------------------------------------
__global__ __launch_bounds__(1024) void transcode_kernel(const float* __restrict__ x,
                                                         void* __restrict__ aos) {
    int n;
    int rr = slab_rr(&n, false);
    const float* __restrict__ ub = x + (size_t)n * kVol;
    f32x2 bx = __builtin_nontemporal_load((const f32x2*)(ub + rr));
    f32x2 by = __builtin_nontemporal_load((const f32x2*)(ub + kPlane + rr));
    f32x2 bz = __builtin_nontemporal_load((const f32x2*)(ub + 2 * kPlane + rr));
    bx *= kScale0; by *= kScale0; bz *= kScale0;
    u32x3 s;
    s.x = f2h2(bx.x, by.x);      // x0,y0
    s.y = f2h2(bz.x, bz.y);      // z0,z1
    s.z = f2h2(bx.y, by.y);      // x1,y1
    char* ob = (char*)aos + (size_t)n * kBatchBytes;
    *(u32x3*)(ob + (size_t)(rr >> 1) * 12) = s;    // 12B store, 4B-aligned
}

// ---------------------------------------------------------------------------
// Warp step on pair-packed fp16. MODE 1: -> pairs. MODE 2: -> f32 SoA
// d_out (final, nontemporal stores).
// ---------------------------------------------------------------------------
template <int MODE, bool REV>
__global__ __launch_bounds__(1024) void step_p6h(const void* __restrict__ uin,
                                                 void* __restrict__ uout) {
    int n;
    int rr = slab_rr(&n, REV);
    int w = rr & 127;
    int h = (rr >> 7) & 127;
    int d = rr >> 14;

    const char* __restrict__ ubase = (const char*)uin + (size_t)n * kBatchBytes;

    // Base velocity for voxels (rr, rr+1): one 12B dwordx3 (even pair:
    // d0=x0y0, d1=z0z1, d2=x1y1).
    u32x3 bq = *(const u32x3*)(ubase + (size_t)(rr >> 1) * 12);
    float vx[2], vy[2], vz[2];
    vx[0] = h2f(bq.x & 0xffffu); vy[0] = h2f(bq.x >> 16); vz[0] = h2f(bq.y & 0xffffu);
    vx[1] = h2f(bq.z & 0xffffu); vy[1] = h2f(bq.z >> 16); vz[1] = h2f(bq.y >> 16);

    // Cube offsets + weights (border clamp folded into low corner).
    int   o[2];
    float wxa[2], wya[2], wza[2];
    #pragma unroll
    for (int j = 0; j < 2; ++j) {
        float px = fminf(fmaxf((float)(w + j) + vx[j] * 63.5f, 0.0f), 127.0f);
        float py = fminf(fmaxf((float)h       + vy[j] * 63.5f, 0.0f), 127.0f);
        float pz = fminf(fmaxf((float)d       + vz[j] * 63.5f, 0.0f), 127.0f);
        int x0 = min((int)floorf(px), 126);
        int y0 = min((int)floorf(py), 126);
        int z0 = min((int)floorf(pz), 126);
        wxa[j] = px - (float)x0;
        wya[j] = py - (float)y0;
        wza[j] = pz - (float)z0;
        o[j] = (z0 << 14) + (y0 << 7) + x0;
    }

    // Row byte offsets: +128 voxels = 64 pairs = 768B; +16384 voxels = 98304B.
    const int rowbyte[4] = {0, 768, 98304, 99072};
    float res[3][2];
    #pragma unroll
    for (int j = 0; j < 2; ++j) {
        float wx = wxa[j], wy = wya[j], wz = wza[j];
        float omx = 1.0f - wx, omy = 1.0f - wy, omz = 1.0f - wz;
        u32 pb = (u32)(o[j] & 1);
        size_t gb = (size_t)(o[j] >> 1) * 12 + (pb << 2);
        float cr[4][3];
        #pragma unroll
        for (int r = 0; r < 4; ++r) {
            u32x4a4 q = *(const u32x4a4*)(ubase + gb + rowbyte[r]);
            // even (pb=0): q = d0(k) d1(k) d2(k) d0(k+1)
            // odd  (pb=1): q = d1(k) d2(k) d0(k+1) d1(k+1)
            u32 xy0 = pb ? q.y : q.x;
            u32 z0b = pb ? (q.x >> 16) : (q.y & 0xffffu);
            u32 xy1 = q.z;
            u32 z1b = pb ? (q.w & 0xffffu) : (q.y >> 16);
            float ax = h2f(xy0 & 0xffffu), ay = h2f(xy0 >> 16), az = h2f(z0b);
            float bx = h2f(xy1 & 0xffffu), by = h2f(xy1 >> 16), bz = h2f(z1b);
            cr[r][0] = ax * omx + bx * wx;
            cr[r][1] = ay * omx + by * wx;
            cr[r][2] = az * omx + bz * wx;
        }
        #pragma unroll
        for (int c = 0; c < 3; ++c) {
            float c0 = cr[0][c] * omy + cr[1][c] * wy;
            float c1 = cr[2][c] * omy + cr[3][c] * wy;
            float base = (c == 0) ? vx[j] : (c == 1) ? vy[j] : vz[j];
            res[c][j] = base + (c0 * omz + c1 * wz);
        }
    }

    if constexpr (MODE == 2) {
        // Final step: f32 SoA into d_out (written exactly once, never read
        // again on-device) -- nontemporal to protect the A-buffer's L2 lines.
        float* __restrict__ obp = (float*)uout + (size_t)n * kVol;
        __builtin_nontemporal_store(f32x2{res[0][0], res[0][1]}, (f32x2*)(obp + rr));
        __builtin_nontemporal_store(f32x2{res[1][0], res[1][1]}, (f32x2*)(obp + kPlane + rr));
        __builtin_nontemporal_store(f32x2{res[2][0], res[2][1]}, (f32x2*)(obp + 2 * kPlane + rr));
    } else {
        u32x3 s;
        s.x = f2h2(res[0][0], res[1][0]);   // x0,y0
        s.y = f2h2(res[2][0], res[2][1]);   // z0,z1
        s.z = f2h2(res[0][1], res[1][1]);   // x1,y1
        char* ob = (char*)uout + (size_t)n * kBatchBytes;
        *(u32x3*)(ob + (size_t)(rr >> 1) * 12) = s;
    }
}

// ---------------------------------------------------------------------------
// R7 f32 SoA kernel retained verbatim as the small-workspace fallback.
// ---------------------------------------------------------------------------
template <bool SCALED>
__global__ __launch_bounds__(256) void step_kernel(const float* __restrict__ u,
                                                   float* __restrict__ out) {
    int b    = blockIdx.x;
    int xcd  = b & 7;
    int seq  = b >> 3;
    int slab = xcd | ((seq >> 9) << 3);
    int n    = slab >> 3;
    int dblk = slab & 7;
    int vo   = ((seq & 511) << 9) | (threadIdx.x << 1);
    int rr   = (dblk << 18) | vo;

    int w = rr & 127;
    int h = (rr >> 7) & 127;
    int d = rr >> 14;

    const float* __restrict__ ub = u + (size_t)n * kVol;

    f32x2 bx = *(const f32x2*)(ub + rr);
    f32x2 by = *(const f32x2*)(ub + kPlane + rr);
    f32x2 bz = *(const f32x2*)(ub + 2 * kPlane + rr);
    if (SCALED) { bx *= kScale0; by *= kScale0; bz *= kScale0; }

    int   o[2];
    float wxa[2], wya[2], wza[2];
    #pragma unroll
    for (int j = 0; j < 2; ++j) {
        float vx = (j == 0) ? bx.x : bx.y;
        float vy = (j == 0) ? by.x : by.y;
        float vz = (j == 0) ? bz.x : bz.y;
        float px = fminf(fmaxf((float)(w + j) + vx * 63.5f, 0.0f), 127.0f);
        float py = fminf(fmaxf((float)h       + vy * 63.5f, 0.0f), 127.0f);
        float pz = fminf(fmaxf((float)d       + vz * 63.5f, 0.0f), 127.0f);
        int x0 = min((int)floorf(px), 126);
        int y0 = min((int)floorf(py), 126);
        int z0 = min((int)floorf(pz), 126);
        wxa[j] = px - (float)x0;
        wya[j] = py - (float)y0;
        wza[j] = pz - (float)z0;
        o[j] = (z0 << 14) + (y0 << 7) + x0;
    }

    const int rowoff[4] = {0, 128, 16384, 16512};
    float res[3][2];
    #pragma unroll
    for (int j = 0; j < 2; ++j) {
        float wx = wxa[j], wy = wya[j], wz = wza[j];
        float omx = 1.0f - wx, omy = 1.0f - wy, omz = 1.0f - wz;
        #pragma unroll
        for (int c = 0; c < 3; ++c) {
            const float* __restrict__ up = ub + c * kPlane;
            f32x2 v00 = *(const f32x2*)(up + o[j] + rowoff[0]);
            f32x2 v01 = *(const f32x2*)(up + o[j] + rowoff[1]);
            f32x2 v10 = *(const f32x2*)(up + o[j] + rowoff[2]);
            f32x2 v11 = *(const f32x2*)(up + o[j] + rowoff[3]);
            if (SCALED) { v00 *= kScale0; v01 *= kScale0; v10 *= kScale0; v11 *= kScale0; }
            float c00 = v00.x * omx + v00.y * wx;
            float c01 = v01.x * omx + v01.y * wx;
            float c10 = v10.x * omx + v10.y * wx;
            float c11 = v11.x * omx + v11.y * wx;
            float c0 = c00 * omy + c01 * wy;
            float c1 = c10 * omy + c11 * wy;
            float s  = c0 * omz + c1 * wz;
            float base = (c == 0) ? ((j == 0) ? bx.x : bx.y)
                       : (c == 1) ? ((j == 0) ? by.x : by.y)
                                  : ((j == 0) ? bz.x : bz.y);
            res[c][j] = base + s;
        }
    }

    float* __restrict__ ob = out + (size_t)n * kVol;
    *(f32x2*)(ob + rr)              = f32x2{res[0][0], res[0][1]};
    *(f32x2*)(ob + kPlane + rr)     = f32x2{res[1][0], res[1][1]};
    *(f32x2*)(ob + 2 * kPlane + rr) = f32x2{res[2][0], res[2][1]};
}

extern "C" void kernel_launch(void* const* d_in, const int* in_sizes, int n_in,
                              void* d_out, int out_size, void* d_ws, size_t ws_size,
                              hipStream_t stream) {
    const float* x = (const float*)d_in[0];
    float* out = (float*)d_out;

    const int grd = kTotalVox / (1024 * 2);  // 2048 blocks of 1024 threads
    // Two pair-packed buffers: 2 x 25,165,824 B (+4KB slack).
    const size_t need_p6 = (size_t)2 * kN * kBatchBytes + 4096;

    if (ws_size >= need_p6) {
        char* A = (char*)d_ws;
        char* B = A + (size_t)kN * kBatchBytes;
        transcode_kernel<<<grd, 1024, 0, stream>>>(x, A);        // u0 (asc)
        step_p6h<1, true ><<<grd, 1024, 0, stream>>>(A, B);      // s1 (desc)
        step_p6h<1, false><<<grd, 1024, 0, stream>>>(B, A);      // s2 (asc)
        step_p6h<1, true ><<<grd, 1024, 0, stream>>>(A, B);      // s3 (desc)
        step_p6h<1, false><<<grd, 1024, 0, stream>>>(B, A);      // s4 (asc)
        step_p6h<2, true ><<<grd, 1024, 0, stream>>>(A, out);    // s5 -> d_out
    } else {
        // R3-parity f32 fallback: x->out->ws->out->ws->out.
        float* ws = (float*)d_ws;
        const int g256 = kTotalVox / (256 * 2);
        step_kernel<true ><<<g256, 256, 0, stream>>>(x,   out);
        step_kernel<false><<<g256, 256, 0, stream>>>(out, ws);
        step_kernel<false><<<g256, 256, 0, stream>>>(ws,  out);
        step_kernel<false><<<g256, 256, 0, stream>>>(out, ws);
        step_kernel<false><<<g256, 256, 0, stream>>>(ws,  out);
    }
}